// Round 1
// baseline (109.614 us; speedup 1.0000x reference)
//
#include <hip/hip_runtime.h>

#define Bsz 256
#define Pn  2048
#define En  16
#define HIDn 128
#define OUTn 128
#define BN_EPS 1e-5f

// ---------------------------------------------------------------------------
// K1: per-batch SLayer (both homology dims) + x@W1 + BN1 stat accumulation
// grid = B blocks, 256 threads
// ---------------------------------------------------------------------------
__global__ __launch_bounds__(256) void k_slayer_w1(
    const float* __restrict__ pts0, const int* __restrict__ cnt0,
    const float* __restrict__ pts1, const int* __restrict__ cnt1,
    const float* __restrict__ c0, const float* __restrict__ ls0,
    const float* __restrict__ c1, const float* __restrict__ ls1,
    const float* __restrict__ W1,
    float* __restrict__ u, float* __restrict__ sum1, float* __restrict__ sumsq1)
{
    __shared__ float cen[2][En][2];
    __shared__ float shp[2][En][2];
    __shared__ float red[4][32];
    __shared__ float xrow[32];

    const int tid = threadIdx.x;
    const int b   = blockIdx.x;

    // load centers + softplus(log_sharp)+1e-6 into LDS (64 values total)
    if (tid < 64) {
        int h = tid >> 5, r = tid & 31, e = r >> 1, d = r & 1;
        const float* C = h ? c1 : c0;
        const float* L = h ? ls1 : ls0;
        cen[h][e][d] = C[e * 2 + d];
        float z  = L[e * 2 + d];
        float sp = (z > 20.f) ? z : logf(1.f + expf(z));
        shp[h][e][d] = sp + 1e-6f;
    }
    __syncthreads();

    float acc0[En], acc1[En];
    #pragma unroll
    for (int e = 0; e < En; e++) { acc0[e] = 0.f; acc1[e] = 0.f; }

    const int n0 = cnt0[b];
    const int n1 = cnt1[b];
    const float2* p0 = (const float2*)pts0 + (size_t)b * Pn;
    const float2* p1 = (const float2*)pts1 + (size_t)b * Pn;

    for (int p = tid; p < n0; p += 256) {
        float2 pt = p0[p];
        #pragma unroll
        for (int e = 0; e < En; e++) {
            float dx = pt.x - cen[0][e][0];
            float dy = pt.y - cen[0][e][1];
            float t  = shp[0][e][0] * dx * dx + shp[0][e][1] * dy * dy;
            acc0[e] += __expf(-t);
        }
    }
    for (int p = tid; p < n1; p += 256) {
        float2 pt = p1[p];
        #pragma unroll
        for (int e = 0; e < En; e++) {
            float dx = pt.x - cen[1][e][0];
            float dy = pt.y - cen[1][e][1];
            float t  = shp[1][e][0] * dx * dx + shp[1][e][1] * dy * dy;
            acc1[e] += __expf(-t);
        }
    }

    // reduce 32 accumulators across the wave (64 lanes)
    #pragma unroll
    for (int e = 0; e < En; e++) {
        #pragma unroll
        for (int off = 32; off > 0; off >>= 1) {
            acc0[e] += __shfl_down(acc0[e], off, 64);
            acc1[e] += __shfl_down(acc1[e], off, 64);
        }
    }
    const int wave = tid >> 6, lane = tid & 63;
    if (lane == 0) {
        #pragma unroll
        for (int e = 0; e < En; e++) { red[wave][e] = acc0[e]; red[wave][16 + e] = acc1[e]; }
    }
    __syncthreads();
    if (tid < 32) xrow[tid] = red[0][tid] + red[1][tid] + red[2][tid] + red[3][tid];
    __syncthreads();

    // u[b,:] = xrow @ W1  (W1 is [32,128] row-major; coalesced over tid)
    if (tid < HIDn) {
        float a = 0.f;
        #pragma unroll
        for (int k = 0; k < 32; k++) a = fmaf(xrow[k], W1[k * HIDn + tid], a);
        u[b * HIDn + tid] = a;
        atomicAdd(&sum1[tid], a);
        atomicAdd(&sumsq1[tid], a * a);
    }
}

// ---------------------------------------------------------------------------
// K2: BN1 (stats from atomically-accumulated sums) + ReLU + h@W2 + BN2 stats
// grid = B blocks, 128 threads
// ---------------------------------------------------------------------------
__global__ __launch_bounds__(128) void k_bn1_w2(
    const float* __restrict__ u, const float* __restrict__ W2,
    const float* __restrict__ g1, const float* __restrict__ be1,
    const float* __restrict__ sum1, const float* __restrict__ sumsq1,
    float* __restrict__ ypre, float* __restrict__ sum2, float* __restrict__ sumsq2)
{
    __shared__ float hrow[HIDn];
    const int j = threadIdx.x, b = blockIdx.x;

    float uv   = u[b * HIDn + j];
    float m    = sum1[j] * (1.f / Bsz);
    float var  = sumsq1[j] * (1.f / Bsz) - m * m;
    float rstd = rsqrtf(var + BN_EPS);
    float h    = fmaxf((uv - m) * rstd * g1[j] + be1[j], 0.f);
    hrow[j] = h;
    __syncthreads();

    float a = 0.f;
    #pragma unroll 8
    for (int k = 0; k < HIDn; k++) a = fmaf(hrow[k], W2[k * OUTn + j], a);

    ypre[b * OUTn + j] = a;
    atomicAdd(&sum2[j], a);
    atomicAdd(&sumsq2[j], a * a);
}

// ---------------------------------------------------------------------------
// K3: BN2 + row L2-normalize + write output
// grid = B blocks, 128 threads
// ---------------------------------------------------------------------------
__global__ __launch_bounds__(128) void k_bn2_norm(
    const float* __restrict__ ypre,
    const float* __restrict__ g2, const float* __restrict__ be2,
    const float* __restrict__ sum2, const float* __restrict__ sumsq2,
    float* __restrict__ out)
{
    __shared__ float part[2];
    const int j = threadIdx.x, b = blockIdx.x;

    float yv   = ypre[b * OUTn + j];
    float m    = sum2[j] * (1.f / Bsz);
    float var  = sumsq2[j] * (1.f / Bsz) - m * m;
    float rstd = rsqrtf(var + BN_EPS);
    float y    = (yv - m) * rstd * g2[j] + be2[j];

    float sq = y * y;
    #pragma unroll
    for (int off = 32; off > 0; off >>= 1) sq += __shfl_down(sq, off, 64);
    if ((j & 63) == 0) part[j >> 6] = sq;
    __syncthreads();
    float total = part[0] + part[1];
    float norm  = fmaxf(sqrtf(total), 1e-12f);
    out[b * OUTn + j] = y / norm;
}

extern "C" void kernel_launch(void* const* d_in, const int* in_sizes, int n_in,
                              void* d_out, int out_size, void* d_ws, size_t ws_size,
                              hipStream_t stream) {
    const float* pts0 = (const float*)d_in[0];
    const int*   cnt0 = (const int*)  d_in[1];
    const float* pts1 = (const float*)d_in[2];
    const int*   cnt1 = (const int*)  d_in[3];
    const float* c0   = (const float*)d_in[4];
    const float* ls0  = (const float*)d_in[5];
    const float* c1   = (const float*)d_in[6];
    const float* ls1  = (const float*)d_in[7];
    const float* W1   = (const float*)d_in[8];
    const float* g1   = (const float*)d_in[9];
    const float* be1  = (const float*)d_in[10];
    const float* W2   = (const float*)d_in[11];
    const float* g2   = (const float*)d_in[12];
    const float* be2  = (const float*)d_in[13];
    float* out = (float*)d_out;

    float* ws     = (float*)d_ws;
    float* u      = ws;                  // B*HID   = 32768 floats
    float* ypre   = ws + 32768;          // B*OUT   = 32768 floats
    float* sum1   = ws + 65536;          // 128
    float* sumsq1 = sum1 + 128;          // 128
    float* sum2   = sumsq1 + 128;        // 128
    float* sumsq2 = sum2 + 128;          // 128

    // zero the 4 stat arrays (ws is poisoned 0xAA before every timed call)
    hipMemsetAsync(sum1, 0, 512 * sizeof(float), stream);

    k_slayer_w1<<<Bsz, 256, 0, stream>>>(pts0, cnt0, pts1, cnt1,
                                         c0, ls0, c1, ls1, W1,
                                         u, sum1, sumsq1);
    k_bn1_w2<<<Bsz, 128, 0, stream>>>(u, W2, g1, be1, sum1, sumsq1,
                                      ypre, sum2, sumsq2);
    k_bn2_norm<<<Bsz, 128, 0, stream>>>(ypre, g2, be2, sum2, sumsq2, out);
}